// Round 4
// baseline (670.031 us; speedup 1.0000x reference)
//
#include <hip/hip_runtime.h>
#include <hip/hip_bf16.h>
#include <math.h>

typedef __hip_bfloat16 bf16;
#define DEV __device__ __forceinline__

DEV float bf2f(bf16 h){ return __bfloat162float(h); }
DEV bf16 f2bf(float f){ return __float2bfloat16(f); }

// dual-dtype input load: md=1 -> f32, md=0 -> bf16
DEV float ld(const void* p, size_t i, int md){
  return md ? ((const float*)p)[i] : bf2f(((const bf16*)p)[i]);
}

DEV float wred(float v){
  #pragma unroll
  for(int off=32; off>0; off>>=1) v += __shfl_down(v, off, 64);
  return __shfl(v, 0, 64);
}

// ---------------- K0: detect input dtype (f32 mantissa halves decode huge as bf16)
__global__ __launch_bounds__(256) void k_detect(const unsigned short* __restrict__ xr, int* __restrict__ flag){
  __shared__ float sm[256];
  int t = threadIdx.x;
  float m = 0.f;
  for(int i=t;i<8192;i+=256){
    unsigned int w = ((unsigned int)xr[i]) << 16;
    float v = fabsf(__uint_as_float(w));
    if(v != v) v = 1e30f;
    m = fmaxf(m, v);
  }
  sm[t] = m; __syncthreads();
  if(t == 0){
    float mm = 0.f;
    for(int i=0;i<256;i++) mm = fmaxf(mm, sm[i]);
    *flag = (mm > 1e10f) ? 1 : 0;
  }
}

// ---------------- K1: LayerNorm over C=256 of x[B,C,L] -> xnorm[B,L,256] (bf16)
__global__ __launch_bounds__(256) void k_ln1(const void* __restrict__ x, const void* __restrict__ gam,
                                             const void* __restrict__ bet, bf16* __restrict__ xnb,
                                             const int* __restrict__ modep){
  const int md = *modep;
  int lane = threadIdx.x & 63, wv = threadIdx.x >> 6;
  int row = blockIdx.x*4 + wv;                  // b*4096 + l
  int b = row >> 12, l = row & 4095;
  size_t xb = ((size_t)b << 20) + l;            // + c*4096
  float v[4], s=0.f, s2=0.f;
  #pragma unroll
  for(int i=0;i<4;i++){
    int c = lane + (i<<6);
    v[i] = ld(x, xb + ((size_t)c << 12), md);
    s += v[i]; s2 += v[i]*v[i];
  }
  s = wred(s); s2 = wred(s2);
  float mu = s*(1.f/256.f);
  float rs = rsqrtf(s2*(1.f/256.f) - mu*mu + 1e-5f);
  bf16* o = xnb + (size_t)row*256;
  #pragma unroll
  for(int i=0;i<4;i++){
    int c = lane + (i<<6);
    o[c] = f2bf((v[i]-mu)*rs*ld(gam,c,md) + ld(bet,c,md));
  }
}

// ---------------- K2: in_proj (M=65536,K=64,N=256 split xc/z). grid: bm(16) x lt(128) x eh(2)
__global__ __launch_bounds__(256) void k_inproj(const bf16* __restrict__ xnb, const void* __restrict__ w,
                                                bf16* __restrict__ xcb, bf16* __restrict__ zb,
                                                const int* __restrict__ modep){
  __shared__ float At[64*36];     // [k][l: 32+pad]
  __shared__ float Wt[64*132];    // [k][e: 128+pad]
  const int md = *modep;
  int t = threadIdx.x;
  int eh = blockIdx.x & 1;
  int lt = (blockIdx.x >> 1) & 127;
  int bm = blockIdx.x >> 8;
  int p = bm >> 2, b = bm & 3, l0 = lt << 5, e0 = eh << 7;
  for(int idx = t; idx < 8192; idx += 256){
    int e = idx >> 6, d = idx & 63;
    Wt[d*132 + e] = ld(w, (size_t)(e0 + e)*64 + d, md);
  }
  for(int idx = t; idx < 2048; idx += 256){
    int l = idx >> 6, d = idx & 63;
    At[d*36 + l] = bf2f(xnb[((size_t)(b*4096 + l0 + l))*256 + p*64 + d]);
  }
  __syncthreads();
  int lq = t & 7, eg = t >> 3;    // 4 l x 4 e
  float acc[4][4] = {};
  for(int k=0;k<64;k++){
    float4 a  = *(const float4*)&At[k*36 + (lq<<2)];
    float4 w4 = *(const float4*)&Wt[k*132 + (eg<<2)];
    float av[4] = {a.x,a.y,a.z,a.w};
    float wv[4] = {w4.x,w4.y,w4.z,w4.w};
    #pragma unroll
    for(int i=0;i<4;i++)
      #pragma unroll
      for(int j=0;j<4;j++) acc[i][j] = fmaf(av[i], wv[j], acc[i][j]);
  }
  bf16* dst = eh ? zb : xcb;      // each half is [16][4096][128]
  #pragma unroll
  for(int i=0;i<4;i++){
    size_t ro = ((size_t)bm*4096 + l0 + (lq<<2) + i)*128 + (eg<<2);
    __align__(8) bf16 tmp[4];
    #pragma unroll
    for(int j=0;j<4;j++) tmp[j] = f2bf(acc[i][j]);
    *(ushort4*)&dst[ro] = *(ushort4*)tmp;
  }
}

// ---------------- K3: causal depthwise conv1d(4) + bias + SiLU -> xs[bm,l,128] (bf16)
__global__ __launch_bounds__(256) void k_conv(const bf16* __restrict__ xcb, const void* __restrict__ cw,
                                              const void* __restrict__ cb, bf16* __restrict__ xsb,
                                              const int* __restrict__ modep){
  const int md = *modep;
  int g = blockIdx.x*256 + threadIdx.x;     // 16*4096*128
  int d = g & 127;
  int bl = g >> 7;
  int l = bl & 4095;
  int bm = bl >> 12;
  float acc = ld(cb, d, md);
  #pragma unroll
  for(int j=0;j<4;j++){
    int ll = l - 3 + j;
    if(ll >= 0) acc = fmaf(bf2f(xcb[((size_t)bm*4096 + ll)*128 + d]), ld(cw, (d<<2)+j, md), acc);
  }
  xsb[g] = f2bf(acc / (1.f + __expf(-acc)));
}

// ---------------- K4: x_proj  xdbl[bm,l,36] = xs @ W^T   (K=128,N=36)  f32 out
__global__ __launch_bounds__(256) void k_xproj(const bf16* __restrict__ xsb, const void* __restrict__ w,
                                               float* __restrict__ xdbl, const int* __restrict__ modep){
  __shared__ float At[128*68];
  __shared__ float Ww[128*40];
  const int md = *modep;
  int t = threadIdx.x;
  int bm = blockIdx.x >> 6, lt = blockIdx.x & 63, l0 = lt << 6;
  for(int idx = t; idx < 4608; idx += 256){
    int e = idx >> 7, k = idx & 127;
    Ww[k*40 + e] = ld(w, idx, md);
  }
  for(int idx = t; idx < 8192; idx += 256){
    int l = idx >> 7, k = idx & 127;
    At[k*68 + l] = bf2f(xsb[((size_t)bm*4096 + l0 + l)*128 + k]);
  }
  __syncthreads();
  int l = t & 63, eg = t >> 6;
  float acc[9] = {};
  for(int k=0;k<128;k++){
    float a = At[k*68 + l];
    #pragma unroll
    for(int j=0;j<9;j++) acc[j] = fmaf(a, Ww[k*40 + eg*9 + j], acc[j]);
  }
  float* o = xdbl + ((size_t)bm*4096 + l0 + l)*36 + eg*9;
  #pragma unroll
  for(int j=0;j<9;j++) o[j] = acc[j];
}

// ---------------- K5a: scan phase1 — per-chunk local state S (bf16), decay P (f32)
__global__ __launch_bounds__(128) void k_scan1(const bf16* __restrict__ xsb, const float* __restrict__ xdbl,
                                               const void* __restrict__ dtw, const void* __restrict__ dtb,
                                               const void* __restrict__ Alog,
                                               float* __restrict__ CP, bf16* __restrict__ CSb,
                                               const int* __restrict__ modep){
  __shared__ float sh[2304];      // 64 rows x 36 (dt 0..3 | B 4..19 | C 20..35)
  const int md = *modep;
  int d = threadIdx.x;
  int bm = blockIdx.x >> 6, c = blockIdx.x & 63;
  size_t row0 = (size_t)bm*4096 + (c<<6);
  for(int idx = d; idx < 2304; idx += 128) sh[idx] = xdbl[row0*36 + idx];
  float A[16];
  #pragma unroll
  for(int s=0;s<16;s++) A[s] = -expf(ld(Alog, (d<<4)+s, md));
  float wdt[4];
  #pragma unroll
  for(int j=0;j<4;j++) wdt[j] = ld(dtw, (d<<2)+j, md);
  float bdt = ld(dtb, d, md);
  __syncthreads();
  float h[16] = {};
  float sumd = 0.f;
  for(int tt=0;tt<64;tt++){
    const float* r = sh + tt*36;
    float v = bdt;
    #pragma unroll
    for(int j=0;j<4;j++) v = fmaf(r[j], wdt[j], v);
    float dv = (v > 15.f) ? v : log1pf(__expf(v));
    float u = bf2f(xsb[(row0 + tt)*128 + d]);
    float du = dv*u; sumd += dv;
    #pragma unroll
    for(int s=0;s<16;s++) h[s] = fmaf(h[s], __expf(dv*A[s]), du*r[4+s]);
  }
  size_t ob = ((size_t)(bm*64 + c)*128 + d) << 4;
  #pragma unroll
  for(int s=0;s<16;s++){ CP[ob+s] = __expf(sumd*A[s]); CSb[ob+s] = f2bf(h[s]); }
}

// ---------------- K5b: scan phase2 — combine 64 chunks; CP[c] becomes h_start of chunk c
__global__ __launch_bounds__(256) void k_scan2(float* __restrict__ CP, const bf16* __restrict__ CSb){
  int g = blockIdx.x*256 + threadIdx.x;   // 32768 = 16*128*16
  int bm = g >> 11, ds = g & 2047;
  float h = 0.f;
  for(int c=0;c<64;c++){
    size_t idx = ((size_t)(bm*64 + c) << 11) + ds;
    float P = CP[idx], S = bf2f(CSb[idx]);
    CP[idx] = h;
    h = fmaf(P, h, S);
  }
}

// ---------------- K5c: scan phase3 — true scan, fuse y=(y+u*D)*silu(z); y overwrites z IN-PLACE
__global__ __launch_bounds__(128) void k_scan3(bf16* __restrict__ zb, const bf16* __restrict__ xsb,
                                               const float* __restrict__ xdbl,
                                               const void* __restrict__ dtw, const void* __restrict__ dtb,
                                               const void* __restrict__ Alog, const void* __restrict__ Dw,
                                               const float* __restrict__ CP, const int* __restrict__ modep){
  __shared__ float sh[2304];
  const int md = *modep;
  int d = threadIdx.x;
  int bm = blockIdx.x >> 6, c = blockIdx.x & 63;
  size_t row0 = (size_t)bm*4096 + (c<<6);
  for(int idx = d; idx < 2304; idx += 128) sh[idx] = xdbl[row0*36 + idx];
  float A[16];
  #pragma unroll
  for(int s=0;s<16;s++) A[s] = -expf(ld(Alog, (d<<4)+s, md));
  float wdt[4];
  #pragma unroll
  for(int j=0;j<4;j++) wdt[j] = ld(dtw, (d<<2)+j, md);
  float bdt = ld(dtb, d, md);
  float Dd = ld(Dw, d, md);
  size_t hb = ((size_t)(bm*64 + c)*128 + d) << 4;
  float h[16];
  #pragma unroll
  for(int s=0;s<16;s++) h[s] = CP[hb+s];
  __syncthreads();
  for(int tt=0;tt<64;tt++){
    const float* r = sh + tt*36;
    float v = bdt;
    #pragma unroll
    for(int j=0;j<4;j++) v = fmaf(r[j], wdt[j], v);
    float dv = (v > 15.f) ? v : log1pf(__expf(v));
    size_t base = (row0 + tt)*128 + d;
    float u = bf2f(xsb[base]);
    float zv = bf2f(zb[base]);          // read z ...
    float du = dv*u;
    float y = 0.f;
    #pragma unroll
    for(int s=0;s<16;s++){
      h[s] = fmaf(h[s], __expf(dv*A[s]), du*r[4+s]);
      y = fmaf(h[s], r[20+s], y);
    }
    float yv = (y + u*Dd) * (zv / (1.f + __expf(-zv)));
    zb[base] = f2bf(yv);                // ... write y to same slot (same thread -> safe)
  }
}

// ---------------- K6: out_proj + skip -> ym[b,l,256] (bf16). K=128 split in 2
__global__ __launch_bounds__(256) void k_outproj(const bf16* __restrict__ yb, const bf16* __restrict__ xnb,
                                                 const void* __restrict__ wo, const void* __restrict__ ss,
                                                 bf16* __restrict__ ymb, const int* __restrict__ modep){
  __shared__ float Yt[64*68];
  __shared__ float Wo[64*68];
  const int md = *modep;
  int t = threadIdx.x;
  int bm = blockIdx.x >> 6, lt = blockIdx.x & 63, l0 = lt << 6;
  int p = bm >> 2, b = bm & 3;
  int lq = t & 15, og = t >> 4;   // 4 l x 4 o
  float acc[4][4] = {};
  for(int kb=0;kb<2;kb++){
    __syncthreads();
    for(int idx = t; idx < 4096; idx += 256){
      int l = idx >> 6, dd = idx & 63;
      Yt[dd*68 + l] = bf2f(yb[((size_t)bm*4096 + l0 + l)*128 + kb*64 + dd]);
    }
    for(int idx = t; idx < 4096; idx += 256){
      int o = idx >> 6, dd = idx & 63;
      Wo[dd*68 + o] = ld(wo, (size_t)o*128 + kb*64 + dd, md);
    }
    __syncthreads();
    for(int k=0;k<64;k++){
      float4 a = *(const float4*)&Yt[k*68 + (lq<<2)];
      float4 w = *(const float4*)&Wo[k*68 + (og<<2)];
      float av[4]={a.x,a.y,a.z,a.w}, wv[4]={w.x,w.y,w.z,w.w};
      #pragma unroll
      for(int i=0;i<4;i++)
        #pragma unroll
        for(int j=0;j<4;j++) acc[i][j] = fmaf(av[i], wv[j], acc[i][j]);
    }
  }
  float sv = ld(ss, 0, md);
  #pragma unroll
  for(int i=0;i<4;i++){
    size_t ro = ((size_t)b*4096 + l0 + (lq<<2) + i)*256 + p*64 + (og<<2);
    #pragma unroll
    for(int j=0;j<4;j++) ymb[ro+j] = f2bf(fmaf(sv, bf2f(xnb[ro+j]), acc[i][j]));
  }
}

// ---------------- K7: LayerNorm2 in-place on ym (bf16 rows of 256)
__global__ __launch_bounds__(256) void k_ln2(bf16* __restrict__ ymb, const void* __restrict__ gam,
                                             const void* __restrict__ bet, const int* __restrict__ modep){
  const int md = *modep;
  int lane = threadIdx.x & 63, wv = threadIdx.x >> 6;
  size_t row = (size_t)blockIdx.x*4 + wv;
  bf16* rp = ymb + row*256 + (lane<<2);
  __align__(8) bf16 raw[4];
  *(ushort4*)raw = *(const ushort4*)rp;
  float v[4];
  #pragma unroll
  for(int i=0;i<4;i++) v[i] = bf2f(raw[i]);
  float s = v[0]+v[1]+v[2]+v[3];
  float s2 = v[0]*v[0]+v[1]*v[1]+v[2]*v[2]+v[3]*v[3];
  s = wred(s); s2 = wred(s2);
  float mu = s*(1.f/256.f);
  float rs = rsqrtf(s2*(1.f/256.f) - mu*mu + 1e-5f);
  int c = lane << 2;
  #pragma unroll
  for(int i=0;i<4;i++) raw[i] = f2bf((v[i]-mu)*rs*ld(gam,c+i,md) + ld(bet,c+i,md));
  *(ushort4*)rp = *(ushort4*)raw;
}

// ---------------- K8: proj GEMM (K=256,N=256)+bias, transposed store -> outb[b,o,l] (bf16)
__global__ __launch_bounds__(256) void k_proj(const bf16* __restrict__ ymb, const void* __restrict__ pw,
                                              const void* __restrict__ pb, bf16* __restrict__ outbb,
                                              const int* __restrict__ modep){
  __shared__ float At[64*36];
  __shared__ float Wt[64*132];    // reused as staging [128 o][33] for transposed store
  const int md = *modep;
  int t = threadIdx.x;
  int oh = blockIdx.x & 1;
  int rt = blockIdx.x >> 1;
  int row0 = rt << 5;
  int b = row0 >> 12, l0 = row0 & 4095, o0 = oh << 7;
  int lq = t & 7, og = t >> 3;    // 4 l x 4 o
  float acc[4][4] = {};
  for(int kb=0;kb<4;kb++){
    __syncthreads();
    for(int idx = t; idx < 2048; idx += 256){
      int l = idx >> 6, k = idx & 63;
      At[k*36 + l] = bf2f(ymb[((size_t)row0 + l)*256 + (kb<<6) + k]);
    }
    for(int idx = t; idx < 8192; idx += 256){
      int o = idx >> 6, k = idx & 63;
      Wt[k*132 + o] = ld(pw, ((size_t)(o0 + o) << 8) + (kb<<6) + k, md);
    }
    __syncthreads();
    for(int k=0;k<64;k++){
      float4 a  = *(const float4*)&At[k*36 + (lq<<2)];
      float4 w4 = *(const float4*)&Wt[k*132 + (og<<2)];
      float av[4]={a.x,a.y,a.z,a.w};
      float wv[4]={w4.x,w4.y,w4.z,w4.w};
      #pragma unroll
      for(int i=0;i<4;i++)
        #pragma unroll
        for(int j=0;j<4;j++) acc[i][j] = fmaf(av[i], wv[j], acc[i][j]);
    }
  }
  __syncthreads();
  float* Sl = Wt;                 // [128 o][33]
  #pragma unroll
  for(int j=0;j<4;j++){
    int o = (og<<2) + j;
    float bb = ld(pb, o0 + o, md);
    #pragma unroll
    for(int i=0;i<4;i++) Sl[o*33 + (lq<<2) + i] = acc[i][j] + bb;
  }
  __syncthreads();
  for(int rep=0; rep<16; rep++){
    int o = (t>>5) + (rep<<3);    // 0..127
    int lw = t & 31;
    outbb[((size_t)(b*256 + o0 + o) << 12) + l0 + lw] = f2bf(Sl[o*33 + lw]);
  }
}

// ---------------- K9a: theta = sigmoid(sum_c out[b,c,hw]*tw[c] + tb)   f32 out
__global__ __launch_bounds__(256) void k_theta(const bf16* __restrict__ outbb, const void* __restrict__ tw,
                                               const void* __restrict__ tb, float* __restrict__ theta,
                                               const int* __restrict__ modep){
  const int md = *modep;
  int g = blockIdx.x*256 + threadIdx.x;  // 16384
  int hw = g & 4095, b = g >> 12;
  const bf16* base = outbb + ((size_t)b << 20) + hw;
  float acc = 0.f;
  for(int c=0;c<256;c++) acc = fmaf(bf2f(base[(size_t)c << 12]), ld(tw, c, md), acc);
  acc += ld(tb, 0, md);
  theta[g] = 1.f / (1.f + __expf(-acc));
}

// ---------------- K9b: depthwise 3x3 + CDC + exact GELU -> gbuf (bf16)
__global__ __launch_bounds__(256) void k_cdc(const bf16* __restrict__ outbb, const float* __restrict__ theta,
                                             const void* __restrict__ cw, bf16* __restrict__ gbufb,
                                             const int* __restrict__ modep){
  const int md = *modep;
  int g = blockIdx.x*256 + threadIdx.x;   // 4*256*4096
  int hw = g & 4095;
  int c = (g >> 12) & 255;
  int b = g >> 20;
  int w0 = hw & 63, h0 = hw >> 6;
  float wk[9]; float ks = 0.f;
  #pragma unroll
  for(int j=0;j<9;j++){ wk[j] = ld(cw, c*9 + j, md); ks += wk[j]; }
  const bf16* base = outbb + (((size_t)b*256 + c) << 12);
  float on = 0.f;
  #pragma unroll
  for(int dy=-1;dy<=1;dy++){
    #pragma unroll
    for(int dx=-1;dx<=1;dx++){
      int hh = h0+dy, ww = w0+dx;
      if(hh>=0 && hh<64 && ww>=0 && ww<64)
        on = fmaf(bf2f(base[(hh<<6)+ww]), wk[(dy+1)*3 + dx+1], on);
    }
  }
  float ctr  = bf2f(base[hw]);
  float edge = on - ctr*ks;
  float th   = theta[((size_t)b<<12) + hw];
  float cd   = fmaf(th, edge, on);
  gbufb[g] = f2bf(0.5f * cd * (1.f + erff(cd * 0.70710678118654752f)));
}

// ---------------- K10: 1x1 pw GEMM + residual, dual-dtype store
__global__ __launch_bounds__(256) void k_pw(const bf16* __restrict__ gbufb, const bf16* __restrict__ outbb,
                                            const void* __restrict__ pww, void* __restrict__ outp,
                                            const int* __restrict__ modep){
  __shared__ float Gt[64*68];
  __shared__ float Wp[64*68];
  const int md = *modep;
  int t = threadIdx.x;
  int hwt = blockIdx.x & 63;
  int ob  = (blockIdx.x >> 6) & 3;
  int b   = blockIdx.x >> 8;
  int hw0 = hwt << 6, o0 = ob << 6;
  int hq = t & 15, og = t >> 4;   // 4 hw x 4 o
  float acc[4][4] = {};
  for(int kc=0;kc<4;kc++){
    __syncthreads();
    for(int idx = t; idx < 4096; idx += 256){
      int cc = idx >> 6, hwl = idx & 63;
      Gt[cc*68 + hwl] = bf2f(gbufb[(((size_t)b*256 + (kc<<6) + cc) << 12) + hw0 + hwl]);
    }
    for(int idx = t; idx < 4096; idx += 256){
      int o = idx >> 6, cc = idx & 63;
      Wp[cc*68 + o] = ld(pww, ((size_t)(o0 + o) << 8) + (kc<<6) + cc, md);
    }
    __syncthreads();
    for(int k=0;k<64;k++){
      float4 gv = *(const float4*)&Gt[k*68 + (hq<<2)];
      float4 wv = *(const float4*)&Wp[k*68 + (og<<2)];
      float ga[4]={gv.x,gv.y,gv.z,gv.w}, wa[4]={wv.x,wv.y,wv.z,wv.w};
      #pragma unroll
      for(int j=0;j<4;j++)
        #pragma unroll
        for(int i=0;i<4;i++) acc[j][i] = fmaf(wa[j], ga[i], acc[j][i]);
    }
  }
  #pragma unroll
  for(int j=0;j<4;j++){
    size_t ro = (((size_t)b*256 + o0 + (og<<2) + j) << 12) + hw0 + (hq<<2);
    #pragma unroll
    for(int i=0;i<4;i++){
      float v = acc[j][i] + bf2f(outbb[ro+i]);
      if(md) ((float*)outp)[ro+i] = v;
      else   ((bf16*)outp)[ro+i]  = f2bf(v);
    }
  }
}

extern "C" void kernel_launch(void* const* d_in, const int* in_sizes, int n_in,
                              void* d_out, int out_size, void* d_ws, size_t ws_size,
                              hipStream_t stream){
  const void* x      = d_in[0];
  const void* ln_g   = d_in[1];
  const void* ln_b   = d_in[2];
  const void* inw    = d_in[3];
  const void* convw  = d_in[4];
  const void* convb  = d_in[5];
  const void* xpw    = d_in[6];
  const void* dtw    = d_in[7];
  const void* dtb    = d_in[8];
  const void* Alog   = d_in[9];
  const void* Dw     = d_in[10];
  const void* outw   = d_in[11];
  const void* sscale = d_in[12];
  const void* projw  = d_in[13];
  const void* projb  = d_in[14];
  const void* cdcw   = d_in[15];
  const void* thw    = d_in[16];
  const void* thb    = d_in[17];
  const void* pww    = d_in[18];
  float* ws = (float*)d_ws;

  // ---- Workspace layout, f32 SLOT offsets (verified sizes; total 17,039,361 slots = 65.0 MiB) ----
  // [0        , 2097152 ) xnb   bf16 [4][4096][256]  (4,194,304 elem)     live: ln1..outproj
  // [2097152  , 6291456 ) xcb   bf16 [16][4096][128] (8,388,608 elem)     live: inproj..conv
  //     alias [2097152,4194304) CP   f32  [16][64][128][16]               live: scan1..scan3
  //     alias [4194304,5242880) CSb  bf16 same shape                      live: scan1..scan2
  //     alias [2097152,4194304) ymb  bf16 [4][4096][256]                  live: outproj..proj
  //     alias [4194304,6291456) outbb bf16 [4][256][4096]                 live: proj..pw
  // [6291456  , 10485760) zb    bf16 [16][4096][128]                      live: inproj..scan3 (y in-place ..outproj)
  //     alias [6291456,8388608) gbufb bf16 [4][256][4096]                 live: cdc..pw
  // [10485760 , 14680064) xsb   bf16 [16][4096][128]                      live: conv..scan3
  //     alias [10485760,10502144) theta f32 [4][4096]                     live: theta..cdc
  // [14680064 , 17039360) xdbl  f32  [16][4096][36]                       live: xproj..scan3
  // [17039360]            flag  int
  bf16*  xnb   = (bf16*)(ws);
  bf16*  xcb   = (bf16*)(ws + 2097152);
  float* CP    = ws + 2097152;
  bf16*  CSb   = (bf16*)(ws + 4194304);
  bf16*  ymb   = (bf16*)(ws + 2097152);
  bf16*  outbb = (bf16*)(ws + 4194304);
  bf16*  zb    = (bf16*)(ws + 6291456);
  bf16*  gbufb = (bf16*)(ws + 6291456);
  bf16*  xsb   = (bf16*)(ws + 10485760);
  float* theta = ws + 10485760;
  float* xdbl  = ws + 14680064;
  int*   flag  = (int*)(ws + 17039360);

  k_detect <<<1,    256, 0, stream>>>((const unsigned short*)x, flag);
  k_ln1    <<<4096, 256, 0, stream>>>(x, ln_g, ln_b, xnb, flag);
  k_inproj <<<4096, 256, 0, stream>>>(xnb, inw, xcb, zb, flag);
  k_conv   <<<32768,256, 0, stream>>>(xcb, convw, convb, xsb, flag);
  k_xproj  <<<1024, 256, 0, stream>>>(xsb, xpw, xdbl, flag);
  k_scan1  <<<1024, 128, 0, stream>>>(xsb, xdbl, dtw, dtb, Alog, CP, CSb, flag);
  k_scan2  <<<128,  256, 0, stream>>>(CP, CSb);
  k_scan3  <<<1024, 128, 0, stream>>>(zb, xsb, xdbl, dtw, dtb, Alog, Dw, CP, flag);
  k_outproj<<<1024, 256, 0, stream>>>(zb, xnb, outw, sscale, ymb, flag);
  k_ln2    <<<4096, 256, 0, stream>>>(ymb, ln_g, ln_b, flag);
  k_proj   <<<1024, 256, 0, stream>>>(ymb, projw, projb, outbb, flag);
  k_theta  <<<64,   256, 0, stream>>>(outbb, thw, thb, theta, flag);
  k_cdc    <<<16384,256, 0, stream>>>(outbb, theta, cdcw, gbufb, flag);
  k_pw     <<<1024, 256, 0, stream>>>(gbufb, outbb, pww, d_out, flag);
}

// Round 5
// 450.030 us; speedup vs baseline: 1.4889x; 1.4889x over previous
//
#include <hip/hip_runtime.h>
#include <hip/hip_bf16.h>
#include <math.h>

typedef __hip_bfloat16 bf16;
typedef short bf8_t __attribute__((ext_vector_type(8)));
typedef float f4_t  __attribute__((ext_vector_type(4)));
#define MFMA16(a,b,c) __builtin_amdgcn_mfma_f32_16x16x32_bf16(a,b,c,0,0,0)
#define DEV __device__ __forceinline__

DEV float bf2f(bf16 h){ return __bfloat162float(h); }
DEV bf16 f2bf(float f){ return __float2bfloat16(f); }
DEV float ld(const void* p, size_t i, int md){
  return md ? ((const float*)p)[i] : bf2f(((const bf16*)p)[i]);
}
DEV float wred(float v){
  #pragma unroll
  for(int off=32; off>0; off>>=1) v += __shfl_down(v, off, 64);
  return __shfl(v, 0, 64);
}

// ---------------- K0: detect input dtype (f32 mantissa halves decode huge as bf16)
__global__ __launch_bounds__(256) void k_detect(const unsigned short* __restrict__ xr, int* __restrict__ flag){
  __shared__ float sm[256];
  int t = threadIdx.x;
  float m = 0.f;
  for(int i=t;i<8192;i+=256){
    unsigned int w = ((unsigned int)xr[i]) << 16;
    float v = fabsf(__uint_as_float(w));
    if(v != v) v = 1e30f;
    m = fmaxf(m, v);
  }
  sm[t] = m; __syncthreads();
  if(t == 0){
    float mm = 0.f;
    for(int i=0;i<256;i++) mm = fmaxf(mm, sm[i]);
    *flag = (mm > 1e10f) ? 1 : 0;
  }
}

// ---------------- K0b: convert GEMM weights to bf16 workspace copies
// layout: [0,16384) inw | [16384,24576) outw | [24576,90112) projw | [90112,155648) pww
__global__ __launch_bounds__(256) void k_wcvt(const void* __restrict__ inw, const void* __restrict__ outw,
                                              const void* __restrict__ projw, const void* __restrict__ pww,
                                              bf16* __restrict__ dst, const int* __restrict__ modep){
  const int md = *modep;
  int g = blockIdx.x*256 + threadIdx.x;
  if(g >= 155648) return;
  const void* src; int i;
  if(g < 16384){ src = inw;   i = g; }
  else if(g < 24576){ src = outw;  i = g - 16384; }
  else if(g < 90112){ src = projw; i = g - 24576; }
  else { src = pww; i = g - 90112; }
  dst[g] = f2bf(ld(src, (size_t)i, md));
}

// ---------------- K1: LayerNorm over C=256 of x[B,C,L] -> xnorm[B,L,256] (bf16)
__global__ __launch_bounds__(256) void k_ln1(const void* __restrict__ x, const void* __restrict__ gam,
                                             const void* __restrict__ bet, bf16* __restrict__ xnb,
                                             const int* __restrict__ modep){
  const int md = *modep;
  int lane = threadIdx.x & 63, wv = threadIdx.x >> 6;
  int row = blockIdx.x*4 + wv;
  int b = row >> 12, l = row & 4095;
  size_t xb = ((size_t)b << 20) + l;
  float v[4], s=0.f, s2=0.f;
  #pragma unroll
  for(int i=0;i<4;i++){
    int c = lane + (i<<6);
    v[i] = ld(x, xb + ((size_t)c << 12), md);
    s += v[i]; s2 += v[i]*v[i];
  }
  s = wred(s); s2 = wred(s2);
  float mu = s*(1.f/256.f);
  float rs = rsqrtf(s2*(1.f/256.f) - mu*mu + 1e-5f);
  bf16* o = xnb + (size_t)row*256;
  #pragma unroll
  for(int i=0;i<4;i++){
    int c = lane + (i<<6);
    o[c] = f2bf((v[i]-mu)*rs*ld(gam,c,md) + ld(bet,c,md));
  }
}

// ---------------- K2: in_proj MFMA  (M=65536 rows, K=64, N=256 -> xc|z)
__global__ __launch_bounds__(256) void k_inproj(const bf16* __restrict__ xnb, const bf16* __restrict__ wb,
                                                bf16* __restrict__ xcb, bf16* __restrict__ zb){
  __shared__ bf16 As[64*72];
  __shared__ bf16 Ws[256*72];
  int t = threadIdx.x;
  int bm = blockIdx.x >> 6, lt = blockIdx.x & 63;
  int p = bm >> 2, b = bm & 3, l0 = lt << 6;
  #pragma unroll
  for(int pass=0; pass<2; pass++){
    int idx = t + pass*256, r = idx >> 3, ch = idx & 7;
    *(uint4*)&As[r*72 + ch*8] = *(const uint4*)&xnb[((size_t)(b*4096 + l0 + r))*256 + p*64 + ch*8];
  }
  #pragma unroll
  for(int pass=0; pass<8; pass++){
    int idx = t + pass*256, e = idx >> 3, ch = idx & 7;
    *(uint4*)&Ws[e*72 + ch*8] = *(const uint4*)&wb[(size_t)e*64 + ch*8];
  }
  __syncthreads();
  int lane = t & 63, w = t >> 6, quad = lane >> 4, lr = lane & 15;
  f4_t acc[16];
  #pragma unroll
  for(int nt=0;nt<16;nt++) acc[nt] = (f4_t){0.f,0.f,0.f,0.f};
  #pragma unroll
  for(int kk=0; kk<64; kk+=32){
    bf8_t a = *(const bf8_t*)&As[(w*16 + lr)*72 + kk + quad*8];
    #pragma unroll
    for(int nt=0;nt<16;nt++){
      bf8_t bb = *(const bf8_t*)&Ws[(nt*16 + lr)*72 + kk + quad*8];
      acc[nt] = MFMA16(a, bb, acc[nt]);
    }
  }
  __syncthreads();
  bf16* Sl = Ws;  // [64 l][264]
  #pragma unroll
  for(int nt=0;nt<16;nt++)
    #pragma unroll
    for(int r=0;r<4;r++)
      Sl[(w*16 + quad*4 + r)*264 + nt*16 + lr] = f2bf(acc[nt][r]);
  __syncthreads();
  #pragma unroll
  for(int pass=0; pass<8; pass++){
    int idx = t + pass*256, l = idx >> 5, c16 = idx & 31;
    int e0 = c16*8;
    uint4 v = *(uint4*)&Sl[l*264 + e0];
    size_t row = (size_t)bm*4096 + l0 + l;
    if(e0 < 128) *(uint4*)&xcb[row*128 + e0] = v;
    else         *(uint4*)&zb[row*128 + e0 - 128] = v;
  }
}

// ---------------- K3: causal depthwise conv1d(4) + bias + SiLU -> xs (bf16)
__global__ __launch_bounds__(256) void k_conv(const bf16* __restrict__ xcb, const void* __restrict__ cw,
                                              const void* __restrict__ cb, bf16* __restrict__ xsb,
                                              const int* __restrict__ modep){
  const int md = *modep;
  int g = blockIdx.x*256 + threadIdx.x;
  int d = g & 127;
  int bl = g >> 7;
  int l = bl & 4095;
  int bm = bl >> 12;
  float acc = ld(cb, d, md);
  #pragma unroll
  for(int j=0;j<4;j++){
    int ll = l - 3 + j;
    if(ll >= 0) acc = fmaf(bf2f(xcb[((size_t)bm*4096 + ll)*128 + d]), ld(cw, (d<<2)+j, md), acc);
  }
  xsb[g] = f2bf(acc / (1.f + __expf(-acc)));
}

// ---------------- K4: x_proj  xdbl[bm,l,36] = xs @ W^T   (K=128,N=36)  f32 out
__global__ __launch_bounds__(256) void k_xproj(const bf16* __restrict__ xsb, const void* __restrict__ w,
                                               float* __restrict__ xdbl, const int* __restrict__ modep){
  __shared__ float At[128*68];
  __shared__ float Ww[128*40];
  const int md = *modep;
  int t = threadIdx.x;
  int bm = blockIdx.x >> 6, lt = blockIdx.x & 63, l0 = lt << 6;
  for(int idx = t; idx < 4608; idx += 256){
    int e = idx >> 7, k = idx & 127;
    Ww[k*40 + e] = ld(w, idx, md);
  }
  for(int idx = t; idx < 8192; idx += 256){
    int l = idx >> 7, k = idx & 127;
    At[k*68 + l] = bf2f(xsb[((size_t)bm*4096 + l0 + l)*128 + k]);
  }
  __syncthreads();
  int l = t & 63, eg = t >> 6;
  float acc[9] = {};
  for(int k=0;k<128;k++){
    float a = At[k*68 + l];
    #pragma unroll
    for(int j=0;j<9;j++) acc[j] = fmaf(a, Ww[k*40 + eg*9 + j], acc[j]);
  }
  float* o = xdbl + ((size_t)bm*4096 + l0 + l)*36 + eg*9;
  #pragma unroll
  for(int j=0;j<9;j++) o[j] = acc[j];
}

// ---------------- K5a: scan phase1 — 128 chunks of 32; local state S (bf16), decay P (f32)
__global__ __launch_bounds__(128) void k_scan1(const bf16* __restrict__ xsb, const float* __restrict__ xdbl,
                                               const void* __restrict__ dtw, const void* __restrict__ dtb,
                                               const void* __restrict__ Alog,
                                               float* __restrict__ CP, bf16* __restrict__ CSb,
                                               const int* __restrict__ modep){
  __shared__ float sh[32*36];
  const int md = *modep;
  int d = threadIdx.x;
  int bm = blockIdx.x >> 7, c = blockIdx.x & 127;
  size_t row0 = (size_t)bm*4096 + (c<<5);
  for(int idx = d; idx < 1152; idx += 128) sh[idx] = xdbl[row0*36 + idx];
  float A[16];
  #pragma unroll
  for(int s=0;s<16;s++) A[s] = -expf(ld(Alog, (d<<4)+s, md));
  float wdt[4];
  #pragma unroll
  for(int j=0;j<4;j++) wdt[j] = ld(dtw, (d<<2)+j, md);
  float bdt = ld(dtb, d, md);
  __syncthreads();
  float h[16] = {};
  float sumd = 0.f;
  for(int tt=0;tt<32;tt++){
    const float* r = sh + tt*36;
    float4 dt4 = *(const float4*)r;
    float v = fmaf(dt4.x,wdt[0], fmaf(dt4.y,wdt[1], fmaf(dt4.z,wdt[2], fmaf(dt4.w,wdt[3], bdt))));
    float dv = fmaxf(v,0.f) + __logf(1.f + __expf(-fabsf(v)));
    float u = bf2f(xsb[(row0 + tt)*128 + d]);
    float du = dv*u; sumd += dv;
    float4 B0 = *(const float4*)(r+4),  B1 = *(const float4*)(r+8);
    float4 B2 = *(const float4*)(r+12), B3 = *(const float4*)(r+16);
    float Bv[16] = {B0.x,B0.y,B0.z,B0.w,B1.x,B1.y,B1.z,B1.w,
                    B2.x,B2.y,B2.z,B2.w,B3.x,B3.y,B3.z,B3.w};
    #pragma unroll
    for(int s=0;s<16;s++) h[s] = fmaf(h[s], __expf(dv*A[s]), du*Bv[s]);
  }
  size_t ob = ((size_t)(bm*128 + c)*128 + d) << 4;
  #pragma unroll
  for(int s=0;s<16;s++){ CP[ob+s] = __expf(sumd*A[s]); CSb[ob+s] = f2bf(h[s]); }
}

// ---------------- K5b: scan phase2 — combine 128 chunks; CP[c] becomes h_start of chunk c
__global__ __launch_bounds__(256) void k_scan2(float* __restrict__ CP, const bf16* __restrict__ CSb){
  int g = blockIdx.x*256 + threadIdx.x;   // 32768
  int bm = g >> 11, ds = g & 2047;
  float h = 0.f;
  for(int c=0;c<128;c++){
    size_t idx = ((size_t)(bm*128 + c) << 11) + ds;
    float P = CP[idx], S = bf2f(CSb[idx]);
    CP[idx] = h;
    h = fmaf(P, h, S);
  }
}

// ---------------- K5c: scan phase3 — true scan, fuse y=(y+u*D)*silu(z); y overwrites z in-place
__global__ __launch_bounds__(128) void k_scan3(bf16* __restrict__ zb, const bf16* __restrict__ xsb,
                                               const float* __restrict__ xdbl,
                                               const void* __restrict__ dtw, const void* __restrict__ dtb,
                                               const void* __restrict__ Alog, const void* __restrict__ Dw,
                                               const float* __restrict__ CP, const int* __restrict__ modep){
  __shared__ float sh[32*36];
  const int md = *modep;
  int d = threadIdx.x;
  int bm = blockIdx.x >> 7, c = blockIdx.x & 127;
  size_t row0 = (size_t)bm*4096 + (c<<5);
  for(int idx = d; idx < 1152; idx += 128) sh[idx] = xdbl[row0*36 + idx];
  float A[16];
  #pragma unroll
  for(int s=0;s<16;s++) A[s] = -expf(ld(Alog, (d<<4)+s, md));
  float wdt[4];
  #pragma unroll
  for(int j=0;j<4;j++) wdt[j] = ld(dtw, (d<<2)+j, md);
  float bdt = ld(dtb, d, md);
  float Dd = ld(Dw, d, md);
  size_t hb = ((size_t)(bm*128 + c)*128 + d) << 4;
  float h[16];
  #pragma unroll
  for(int s=0;s<16;s++) h[s] = CP[hb+s];
  __syncthreads();
  for(int tt=0;tt<32;tt++){
    const float* r = sh + tt*36;
    float4 dt4 = *(const float4*)r;
    float v = fmaf(dt4.x,wdt[0], fmaf(dt4.y,wdt[1], fmaf(dt4.z,wdt[2], fmaf(dt4.w,wdt[3], bdt))));
    float dv = fmaxf(v,0.f) + __logf(1.f + __expf(-fabsf(v)));
    size_t base = (row0 + tt)*128 + d;
    float u = bf2f(xsb[base]);
    float zv = bf2f(zb[base]);
    float du = dv*u;
    float4 B0 = *(const float4*)(r+4),  B1 = *(const float4*)(r+8);
    float4 B2 = *(const float4*)(r+12), B3 = *(const float4*)(r+16);
    float4 C0 = *(const float4*)(r+20), C1 = *(const float4*)(r+24);
    float4 C2 = *(const float4*)(r+28), C3 = *(const float4*)(r+32);
    float Bv[16] = {B0.x,B0.y,B0.z,B0.w,B1.x,B1.y,B1.z,B1.w,
                    B2.x,B2.y,B2.z,B2.w,B3.x,B3.y,B3.z,B3.w};
    float Cv[16] = {C0.x,C0.y,C0.z,C0.w,C1.x,C1.y,C1.z,C1.w,
                    C2.x,C2.y,C2.z,C2.w,C3.x,C3.y,C3.z,C3.w};
    float y = 0.f;
    #pragma unroll
    for(int s=0;s<16;s++){
      h[s] = fmaf(h[s], __expf(dv*A[s]), du*Bv[s]);
      y = fmaf(h[s], Cv[s], y);
    }
    float yv = (y + u*Dd) * (zv / (1.f + __expf(-zv)));
    zb[base] = f2bf(yv);
  }
}

// ---------------- K6: out_proj MFMA + skip  (M=65536, K=128, N=64)
__global__ __launch_bounds__(256) void k_outproj(const bf16* __restrict__ yb, const bf16* __restrict__ xnb,
                                                 const bf16* __restrict__ wb, const void* __restrict__ ss,
                                                 bf16* __restrict__ ymb, const int* __restrict__ modep){
  __shared__ bf16 As[64*72];
  __shared__ bf16 Ws[64*72];
  const int md = *modep;
  int t = threadIdx.x;
  int bm = blockIdx.x >> 6, lt = blockIdx.x & 63;
  int p = bm >> 2, b = bm & 3, l0 = lt << 6;
  int lane = t & 63, w = t >> 6, quad = lane >> 4, lr = lane & 15;
  f4_t acc[4];
  #pragma unroll
  for(int nt=0;nt<4;nt++) acc[nt] = (f4_t){0.f,0.f,0.f,0.f};
  for(int kb=0; kb<2; kb++){
    if(kb) __syncthreads();
    int k0 = kb << 6;
    #pragma unroll
    for(int pass=0; pass<2; pass++){
      int idx = t + pass*256, r = idx >> 3, ch = idx & 7;
      *(uint4*)&As[r*72 + ch*8] = *(const uint4*)&yb[((size_t)bm*4096 + l0 + r)*128 + k0 + ch*8];
    }
    #pragma unroll
    for(int pass=0; pass<2; pass++){
      int idx = t + pass*256, o = idx >> 3, ch = idx & 7;
      *(uint4*)&Ws[o*72 + ch*8] = *(const uint4*)&wb[(size_t)o*128 + k0 + ch*8];
    }
    __syncthreads();
    #pragma unroll
    for(int kk=0; kk<64; kk+=32){
      bf8_t a = *(const bf8_t*)&As[(w*16 + lr)*72 + kk + quad*8];
      #pragma unroll
      for(int nt=0;nt<4;nt++){
        bf8_t bb = *(const bf8_t*)&Ws[(nt*16 + lr)*72 + kk + quad*8];
        acc[nt] = MFMA16(a, bb, acc[nt]);
      }
    }
  }
  __syncthreads();
  bf16* Sl = As;   // [64 l][72]
  #pragma unroll
  for(int nt=0;nt<4;nt++)
    #pragma unroll
    for(int r=0;r<4;r++)
      Sl[(w*16 + quad*4 + r)*72 + nt*16 + lr] = f2bf(acc[nt][r]);
  __syncthreads();
  float sv = ld(ss, 0, md);
  #pragma unroll
  for(int pass=0; pass<2; pass++){
    int idx = t + pass*256, l = idx >> 3, ch = idx & 7;
    size_t gi = ((size_t)b*4096 + l0 + l)*256 + p*64 + ch*8;
    uint4 yv = *(uint4*)&Sl[l*72 + ch*8];
    uint4 xv = *(const uint4*)&xnb[gi];
    const bf16* y8 = (const bf16*)&yv;
    const bf16* x8 = (const bf16*)&xv;
    uint4 ov; bf16* o8 = (bf16*)&ov;
    #pragma unroll
    for(int j=0;j<8;j++) o8[j] = f2bf(fmaf(sv, bf2f(x8[j]), bf2f(y8[j])));
    *(uint4*)&ymb[gi] = ov;
  }
}

// ---------------- K7: LayerNorm2 in-place on ym (bf16 rows of 256)
__global__ __launch_bounds__(256) void k_ln2(bf16* __restrict__ ymb, const void* __restrict__ gam,
                                             const void* __restrict__ bet, const int* __restrict__ modep){
  const int md = *modep;
  int lane = threadIdx.x & 63, wv = threadIdx.x >> 6;
  size_t row = (size_t)blockIdx.x*4 + wv;
  bf16* rp = ymb + row*256 + (lane<<2);
  __align__(8) bf16 raw[4];
  *(ushort4*)raw = *(const ushort4*)rp;
  float v[4];
  #pragma unroll
  for(int i=0;i<4;i++) v[i] = bf2f(raw[i]);
  float s = v[0]+v[1]+v[2]+v[3];
  float s2 = v[0]*v[0]+v[1]*v[1]+v[2]*v[2]+v[3]*v[3];
  s = wred(s); s2 = wred(s2);
  float mu = s*(1.f/256.f);
  float rs = rsqrtf(s2*(1.f/256.f) - mu*mu + 1e-5f);
  int c = lane << 2;
  #pragma unroll
  for(int i=0;i<4;i++) raw[i] = f2bf((v[i]-mu)*rs*ld(gam,c+i,md) + ld(bet,c+i,md));
  *(ushort4*)rp = *(ushort4*)raw;
}

// ---------------- K8: proj MFMA (M=16384, K=256, N=256) + bias, transposed store -> outb[b,o,l]
__global__ __launch_bounds__(256) void k_proj(const bf16* __restrict__ ymb, const bf16* __restrict__ wb,
                                              const void* __restrict__ pb, bf16* __restrict__ outbb,
                                              const int* __restrict__ modep){
  __shared__ bf16 As[64*72];
  __shared__ bf16 Ws[256*72];
  const int md = *modep;
  int t = threadIdx.x;
  int row0 = blockIdx.x << 6;
  int b = row0 >> 12, l0 = row0 & 4095;
  int lane = t & 63, w = t >> 6, quad = lane >> 4, lr = lane & 15;
  f4_t acc[16];
  #pragma unroll
  for(int nt=0;nt<16;nt++) acc[nt] = (f4_t){0.f,0.f,0.f,0.f};
  for(int kb=0; kb<4; kb++){
    if(kb) __syncthreads();
    int k0 = kb << 6;
    #pragma unroll
    for(int pass=0; pass<2; pass++){
      int idx = t + pass*256, r = idx >> 3, ch = idx & 7;
      *(uint4*)&As[r*72 + ch*8] = *(const uint4*)&ymb[((size_t)(row0 + r))*256 + k0 + ch*8];
    }
    #pragma unroll
    for(int pass=0; pass<8; pass++){
      int idx = t + pass*256, e = idx >> 3, ch = idx & 7;
      *(uint4*)&Ws[e*72 + ch*8] = *(const uint4*)&wb[(size_t)e*256 + k0 + ch*8];
    }
    __syncthreads();
    #pragma unroll
    for(int kk=0; kk<64; kk+=32){
      bf8_t a = *(const bf8_t*)&As[(w*16 + lr)*72 + kk + quad*8];
      #pragma unroll
      for(int nt=0;nt<16;nt++){
        bf8_t bb = *(const bf8_t*)&Ws[(nt*16 + lr)*72 + kk + quad*8];
        acc[nt] = MFMA16(a, bb, acc[nt]);
      }
    }
  }
  __syncthreads();
  bf16* Sl = Ws;   // [256 o][72 l]
  #pragma unroll
  for(int nt=0;nt<16;nt++){
    float bv = ld(pb, nt*16 + lr, md);
    #pragma unroll
    for(int r=0;r<4;r++)
      Sl[(nt*16 + lr)*72 + w*16 + quad*4 + r] = f2bf(acc[nt][r] + bv);
  }
  __syncthreads();
  #pragma unroll
  for(int pass=0; pass<8; pass++){
    int idx = t + pass*256, o = idx >> 3, ch = idx & 7;
    uint4 v = *(uint4*)&Sl[o*72 + ch*8];
    *(uint4*)&outbb[((size_t)(b*256 + o) << 12) + l0 + ch*8] = v;
  }
}

// ---------------- K9a: theta = sigmoid(sum_c out[b,c,hw]*tw[c] + tb), quad-split reduction
__global__ __launch_bounds__(256) void k_theta(const bf16* __restrict__ outbb, const void* __restrict__ tw,
                                               const void* __restrict__ tb, float* __restrict__ theta,
                                               const int* __restrict__ modep){
  const int md = *modep;
  int g = blockIdx.x*256 + threadIdx.x;  // 65536
  int q = g & 3;
  int hwi = g >> 2;
  int hw = hwi & 4095, b = hwi >> 12;
  const bf16* base = outbb + ((size_t)b << 20) + hw;
  float acc = 0.f;
  #pragma unroll 4
  for(int cc=0;cc<64;cc++){
    int c = q*64 + cc;
    acc = fmaf(bf2f(base[(size_t)c << 12]), ld(tw, c, md), acc);
  }
  acc += __shfl_xor(acc, 1, 64);
  acc += __shfl_xor(acc, 2, 64);
  if(q == 0){
    float v = acc + ld(tb, 0, md);
    theta[((size_t)b << 12) + hw] = 1.f / (1.f + __expf(-v));
  }
}

// ---------------- K9b: depthwise 3x3 + CDC + exact GELU -> gbuf (bf16)
__global__ __launch_bounds__(256) void k_cdc(const bf16* __restrict__ outbb, const float* __restrict__ theta,
                                             const void* __restrict__ cw, bf16* __restrict__ gbufb,
                                             const int* __restrict__ modep){
  const int md = *modep;
  int g = blockIdx.x*256 + threadIdx.x;
  int hw = g & 4095;
  int c = (g >> 12) & 255;
  int b = g >> 20;
  int w0 = hw & 63, h0 = hw >> 6;
  float wk[9]; float ks = 0.f;
  #pragma unroll
  for(int j=0;j<9;j++){ wk[j] = ld(cw, c*9 + j, md); ks += wk[j]; }
  const bf16* base = outbb + (((size_t)b*256 + c) << 12);
  float on = 0.f;
  #pragma unroll
  for(int dy=-1;dy<=1;dy++){
    #pragma unroll
    for(int dx=-1;dx<=1;dx++){
      int hh = h0+dy, ww = w0+dx;
      if(hh>=0 && hh<64 && ww>=0 && ww<64)
        on = fmaf(bf2f(base[(hh<<6)+ww]), wk[(dy+1)*3 + dx+1], on);
    }
  }
  float ctr  = bf2f(base[hw]);
  float edge = on - ctr*ks;
  float th   = theta[((size_t)b<<12) + hw];
  float cd   = fmaf(th, edge, on);
  gbufb[g] = f2bf(0.5f * cd * (1.f + erff(cd * 0.70710678118654752f)));
}

// ---------------- K10: 1x1 pw MFMA (per b: C[256 o][4096 hw], K=256) + residual, dual-dtype store
__global__ __launch_bounds__(256) void k_pw(const bf16* __restrict__ gbufb, const bf16* __restrict__ outbb,
                                            const bf16* __restrict__ wb, void* __restrict__ outp,
                                            const int* __restrict__ modep){
  __shared__ bf16 As[64*72];      // weight tile [64 o][64 c]
  __shared__ bf16 Bs[256*72];     // act tile [256 hw][64 c]
  const int md = *modep;
  int t = threadIdx.x;
  int b  = blockIdx.x >> 6;
  int ot = (blockIdx.x >> 4) & 3;
  int ht = blockIdx.x & 15;
  int o0 = ot << 6, hw0 = ht << 8;
  int lane = t & 63, w = t >> 6, quad = lane >> 4, lr = lane & 15;
  f4_t acc[16];
  #pragma unroll
  for(int nt=0;nt<16;nt++) acc[nt] = (f4_t){0.f,0.f,0.f,0.f};
  for(int kb=0; kb<4; kb++){
    if(kb) __syncthreads();
    int k0 = kb << 6;
    #pragma unroll
    for(int pass=0; pass<2; pass++){
      int idx = t + pass*256, r = idx >> 3, ch = idx & 7;
      *(uint4*)&As[r*72 + ch*8] = *(const uint4*)&wb[(size_t)(o0 + r)*256 + k0 + ch*8];
    }
    #pragma unroll
    for(int pass=0; pass<8; pass++){
      int idx = t + pass*256, cc = idx >> 5, hc = idx & 31;
      uint4 gv = *(const uint4*)&gbufb[((size_t)(b*256 + k0 + cc) << 12) + hw0 + hc*8];
      const bf16* g8 = (const bf16*)&gv;
      #pragma unroll
      for(int j=0;j<8;j++) Bs[(hc*8 + j)*72 + cc] = g8[j];
    }
    __syncthreads();
    #pragma unroll
    for(int kk=0; kk<64; kk+=32){
      bf8_t a = *(const bf8_t*)&As[(w*16 + lr)*72 + kk + quad*8];
      #pragma unroll
      for(int nt=0;nt<16;nt++){
        bf8_t bb = *(const bf8_t*)&Bs[(nt*16 + lr)*72 + kk + quad*8];
        acc[nt] = MFMA16(a, bb, acc[nt]);
      }
    }
  }
  __syncthreads();
  bf16* Sl = Bs;  // [64 o][264 hw]
  #pragma unroll
  for(int nt=0;nt<16;nt++)
    #pragma unroll
    for(int r=0;r<4;r++)
      Sl[(w*16 + quad*4 + r)*264 + nt*16 + lr] = f2bf(acc[nt][r]);
  __syncthreads();
  #pragma unroll
  for(int pass=0; pass<8; pass++){
    int idx = t + pass*256, ol = idx >> 5, c16 = idx & 31;
    size_t ro = ((size_t)(b*256 + o0 + ol) << 12) + hw0 + c16*8;
    uint4 sv = *(uint4*)&Sl[ol*264 + c16*8];
    uint4 rv = *(const uint4*)&outbb[ro];
    const bf16* s8 = (const bf16*)&sv;
    const bf16* r8 = (const bf16*)&rv;
    if(md){
      float4 f0, f1;
      f0.x = bf2f(s8[0]) + bf2f(r8[0]); f0.y = bf2f(s8[1]) + bf2f(r8[1]);
      f0.z = bf2f(s8[2]) + bf2f(r8[2]); f0.w = bf2f(s8[3]) + bf2f(r8[3]);
      f1.x = bf2f(s8[4]) + bf2f(r8[4]); f1.y = bf2f(s8[5]) + bf2f(r8[5]);
      f1.z = bf2f(s8[6]) + bf2f(r8[6]); f1.w = bf2f(s8[7]) + bf2f(r8[7]);
      *(float4*)&((float*)outp)[ro]     = f0;
      *(float4*)&((float*)outp)[ro + 4] = f1;
    } else {
      uint4 ov; bf16* o8 = (bf16*)&ov;
      #pragma unroll
      for(int j=0;j<8;j++) o8[j] = f2bf(bf2f(s8[j]) + bf2f(r8[j]));
      *(uint4*)&((bf16*)outp)[ro] = ov;
    }
  }
}

extern "C" void kernel_launch(void* const* d_in, const int* in_sizes, int n_in,
                              void* d_out, int out_size, void* d_ws, size_t ws_size,
                              hipStream_t stream){
  const void* x      = d_in[0];
  const void* ln_g   = d_in[1];
  const void* ln_b   = d_in[2];
  const void* inw    = d_in[3];
  const void* convw  = d_in[4];
  const void* convb  = d_in[5];
  const void* xpw    = d_in[6];
  const void* dtw    = d_in[7];
  const void* dtb    = d_in[8];
  const void* Alog   = d_in[9];
  const void* Dw     = d_in[10];
  const void* outw   = d_in[11];
  const void* sscale = d_in[12];
  const void* projw  = d_in[13];
  const void* projb  = d_in[14];
  const void* cdcw   = d_in[15];
  const void* thw    = d_in[16];
  const void* thb    = d_in[17];
  const void* pww    = d_in[18];
  float* ws = (float*)d_ws;

  // ---- Workspace layout, f32 SLOT offsets ----
  // [0, 2097152)         xnb  bf16 [4][4096][256]        live ln1..outproj
  // [2097152, 6291456)   xcb  bf16 [16][4096][128]       live inproj..conv
  //    alias             CP   f32  [16][128][128][16]    live scan1..scan3 (4,194,304 slots exact)
  //    alias [2097152,4194304)  ymb bf16 [4][4096][256]  live outproj..proj
  //    alias [4194304,6291456)  outbb bf16 [4][256][4096] live proj..pw
  // [6291456, 10485760)  zb   bf16 [16][4096][128]       live inproj..outproj (y in place)
  //    alias [6291456,8388608)  gbufb bf16 [4][256][4096] live cdc..pw
  // [10485760, 14680064) xsb  bf16 [16][4096][128]       live conv..scan3
  //    alias             theta f32 [4][4096]             live theta..cdc
  // [14680064, 17039360) xdbl f32 [16][4096][36]         live xproj..scan3
  // [17039360]           flag int
  // [17039364, 17117188) bf16 weight copies (155648 elems)
  // CSb (bf16, 4,194,304 elems) lives in d_out (dead scratch until k_pw overwrites it)
  bf16*  xnb   = (bf16*)(ws);
  bf16*  xcb   = (bf16*)(ws + 2097152);
  float* CP    = ws + 2097152;
  bf16*  ymb   = (bf16*)(ws + 2097152);
  bf16*  outbb = (bf16*)(ws + 4194304);
  bf16*  zb    = (bf16*)(ws + 6291456);
  bf16*  gbufb = (bf16*)(ws + 6291456);
  bf16*  xsb   = (bf16*)(ws + 10485760);
  float* theta = ws + 10485760;
  float* xdbl  = ws + 14680064;
  int*   flag  = (int*)(ws + 17039360);
  bf16*  wsb   = (bf16*)(ws + 17039364);
  bf16*  inwb  = wsb;
  bf16*  outwb = wsb + 16384;
  bf16*  projwb= wsb + 24576;
  bf16*  pwwb  = wsb + 90112;
  bf16*  CSb   = (bf16*)d_out;

  k_detect <<<1,    256, 0, stream>>>((const unsigned short*)x, flag);
  k_wcvt   <<<608,  256, 0, stream>>>(inw, outw, projw, pww, wsb, flag);
  k_ln1    <<<4096, 256, 0, stream>>>(x, ln_g, ln_b, xnb, flag);
  k_inproj <<<1024, 256, 0, stream>>>(xnb, inwb, xcb, zb);
  k_conv   <<<32768,256, 0, stream>>>(xcb, convw, convb, xsb, flag);
  k_xproj  <<<1024, 256, 0, stream>>>(xsb, xpw, xdbl, flag);
  k_scan1  <<<2048, 128, 0, stream>>>(xsb, xdbl, dtw, dtb, Alog, CP, CSb, flag);
  k_scan2  <<<128,  256, 0, stream>>>(CP, CSb);
  k_scan3  <<<2048, 128, 0, stream>>>(zb, xsb, xdbl, dtw, dtb, Alog, Dw, CP, flag);
  k_outproj<<<1024, 256, 0, stream>>>(zb, xnb, outwb, sscale, ymb, flag);
  k_ln2    <<<4096, 256, 0, stream>>>(ymb, ln_g, ln_b, flag);
  k_proj   <<<256,  256, 0, stream>>>(ymb, projwb, projb, outbb, flag);
  k_theta  <<<256,  256, 0, stream>>>(outbb, thw, thb, theta, flag);
  k_cdc    <<<16384,256, 0, stream>>>(outbb, theta, cdcw, gbufb, flag);
  k_pw     <<<256,  256, 0, stream>>>(gbufb, outbb, pwwb, d_out, flag);
}